// Round 11
// baseline (146.613 us; speedup 1.0000x reference)
//
#include <hip/hip_runtime.h>
#include <hip/hip_bf16.h>

// B=2, T=2048, C=1024, H=16, D=64, M=B*T=4096
// GEMMs: exact integer math via i8 MFMA (i32 accum, |dot| <= 130K exact).

typedef __attribute__((ext_vector_type(8))) short bf16x8;
typedef __attribute__((ext_vector_type(4))) float f32x4;
typedef __attribute__((ext_vector_type(4))) int i32x4;

__device__ __forceinline__ f32x4 mfma16(bf16x8 a, bf16x8 b, f32x4 c) {
    return __builtin_amdgcn_mfma_f32_16x16x32_bf16(a, b, c, 0, 0, 0);
}

__device__ __forceinline__ i32x4 mfma_i8(i32x4 a, i32x4 b, i32x4 c) {
    return __builtin_amdgcn_mfma_i32_16x16x64_i8(a, b, c, 0, 0, 0);
}

__device__ __forceinline__ unsigned short f2bf(float f) {
    unsigned int u = __float_as_uint(f);
    unsigned int r = (u + 0x7fffu + ((u >> 16) & 1u)) >> 16;
    return (unsigned short)r;
}

__device__ __forceinline__ unsigned int cvtpk_bf16(float lo, float hi) {
    unsigned int r;
    asm("v_cvt_pk_bf16_f32 %0, %1, %2" : "=v"(r) : "v"(lo), "v"(hi));
    return r;
}

__device__ __forceinline__ float exp2_fast(float x) {
    float r;
    asm("v_exp_f32 %0, %1" : "=v"(r) : "v"(x));
    return r;
}

__device__ __forceinline__ void gload_lds16(const void* g, void* l) {
    __builtin_amdgcn_global_load_lds((const __attribute__((address_space(1))) unsigned int*)g,
                                     (__attribute__((address_space(3))) unsigned int*)l, 16, 0, 0);
}

__device__ __forceinline__ int pack4i8(float a, float b, float c, float d) {
    unsigned int u = ((unsigned int)((int)a & 255)) | (((unsigned int)((int)b & 255)) << 8) |
                     (((unsigned int)((int)c & 255)) << 16) | (((unsigned int)((int)d & 255)) << 24);
    return (int)u;
}

__device__ __forceinline__ float wredsum(float v) {
#pragma unroll
    for (int o = 32; o > 0; o >>= 1) v += __shfl_xor(v, o);
    return v;
}
__device__ __forceinline__ float wredmax(float v) {
#pragma unroll
    for (int o = 32; o > 0; o >>= 1) v = fmaxf(v, __shfl_xor(v, o));
    return v;
}

// ---------------- weight absmean partials (deterministic two-pass) ----------
__global__ __launch_bounds__(256) void wabssum(const float* __restrict__ w0, const float* __restrict__ w1,
                                               const float* __restrict__ w2, const float* __restrict__ w3,
                                               float* __restrict__ part) {
    int widx = blockIdx.x >> 5, b = blockIdx.x & 31;
    const float* w = (widx == 0) ? w0 : (widx == 1) ? w1 : (widx == 2) ? w2 : w3;
    const float4* w4 = (const float4*)w;
    int tid = threadIdx.x;
    float s = 0.f;
    int base = b * 8192 + tid;
#pragma unroll
    for (int i = 0; i < 32; ++i) {
        float4 v = w4[base + i * 256];
        s += fabsf(v.x) + fabsf(v.y) + fabsf(v.z) + fabsf(v.w);
    }
    s = wredsum(s);
    __shared__ float red[4];
    int wid = tid >> 6, lid = tid & 63;
    if (lid == 0) red[wid] = s;
    __syncthreads();
    if (tid == 0) part[blockIdx.x] = red[0] + red[1] + red[2] + red[3];
}

// ---------------- ternary weight quant -> i8 {-1,0,1} -----------------------
__global__ __launch_bounds__(256) void wquant(const float* __restrict__ w0, const float* __restrict__ w1,
                                              const float* __restrict__ w2, const float* __restrict__ w3,
                                              const float* __restrict__ part, signed char* __restrict__ wq8) {
    int widx = blockIdx.x >> 6, b = blockIdx.x & 63;
    const float* w = (widx == 0) ? w0 : (widx == 1) ? w1 : (widx == 2) ? w2 : w3;
    float s = 0.f;
#pragma unroll
    for (int i = 0; i < 32; ++i) s += part[widx * 32 + i];
    s = fmaxf(s * (1.f / 1048576.f), 1e-5f);
    float inv = 1.f / s;
    const float4* w4 = (const float4*)w;
    int* dst = (int*)(wq8 + (size_t)widx * 1048576);
    int tid = threadIdx.x;
#pragma unroll
    for (int it = 0; it < 16; ++it) {
        int i4 = b * 4096 + it * 256 + tid;
        float4 v = w4[i4];
        float q0 = fminf(fmaxf(rintf(v.x * inv), -1.f), 1.f);
        float q1 = fminf(fmaxf(rintf(v.y * inv), -1.f), 1.f);
        float q2 = fminf(fmaxf(rintf(v.z * inv), -1.f), 1.f);
        float q3 = fminf(fmaxf(rintf(v.w * inv), -1.f), 1.f);
        dst[i4] = pack4i8(q0, q1, q2, q3);
    }
}

// ------------- fused rmsnorm + per-token absmax quant -> i8 (NP planes) -----
template <int NP>
__global__ __launch_bounds__(256) void actquant(const float* __restrict__ x, const float* __restrict__ g0,
                                                const float* __restrict__ g1, const float* __restrict__ g2,
                                                signed char* __restrict__ aq, float* __restrict__ ascale) {
    int m = blockIdx.x, tid = threadIdx.x;
    int wid = tid >> 6, lid = tid & 63;
    __shared__ float red[4];
    float4 xv = ((const float4*)(x + (size_t)m * 1024))[tid];
    float ss = xv.x * xv.x + xv.y * xv.y + xv.z * xv.z + xv.w * xv.w;
    ss = wredsum(ss);
    if (lid == 0) red[wid] = ss;
    __syncthreads();
    float rstd = rsqrtf((red[0] + red[1] + red[2] + red[3]) * (1.f / 1024.f) + 1e-6f);
    const float* gs[3] = {g0, g1, g2};
#pragma unroll
    for (int p = 0; p < NP; ++p) {
        float4 gv = ((const float4*)gs[p])[tid];
        float a0 = xv.x * gv.x * rstd, a1 = xv.y * gv.y * rstd;
        float a2 = xv.z * gv.z * rstd, a3 = xv.w * gv.w * rstd;
        float am = fmaxf(fmaxf(fabsf(a0), fabsf(a1)), fmaxf(fabsf(a2), fabsf(a3)));
        am = wredmax(am);
        __syncthreads();
        if (lid == 0) red[wid] = am;
        __syncthreads();
        float rm = fmaxf(fmaxf(red[0], red[1]), fmaxf(red[2], red[3]));
        float scale = 127.f / fmaxf(rm, 1e-5f);
        float q0 = fminf(fmaxf(rintf(a0 * scale), -128.f), 127.f);
        float q1 = fminf(fmaxf(rintf(a1 * scale), -128.f), 127.f);
        float q2 = fminf(fmaxf(rintf(a2 * scale), -128.f), 127.f);
        float q3 = fminf(fmaxf(rintf(a3 * scale), -128.f), 127.f);
        ((int*)(aq + (size_t)p * 4194304 + (size_t)m * 1024))[tid] = pack4i8(q0, q1, q2, q3);
        if (tid == 0) ascale[p * 4096 + m] = scale;
    }
}

// ------------- 128x128-tile i8 GEMM core (dbuf + XOR-swizzled LDS) ----------
// BK=128 i8, 256 thr = 2x2 waves, 4x4 16x16 frags/wave, K=1024 -> 8 steps.
// MODE 0: out bf16 [B,H,T,D]; MODE 1: out bf16 [BH,D,T]; MODE 2: out f32 [M,N]
template <int MODE>
__device__ __forceinline__ void gemm_core(const signed char* __restrict__ A,
                                          const float* __restrict__ asc,
                                          const signed char* __restrict__ W, float s_w,
                                          void* __restrict__ outp, int bm, int bn,
                                          char* As, char* Bs) {
    int tid = threadIdx.x;
    int w = tid >> 6, l = tid & 63;
    int wr = w >> 1, wc = w & 1;
    int lr = l & 15, lh = l >> 4;
    i32x4 acc[4][4] = {};
    int srow = l >> 3;                    // 0..7
    int scolb = (((l & 7) ^ srow)) * 16;  // pre-swizzled source col (bytes)
    int key16 = (lr & 7) * 16;            // read-side XOR key (bytes)
    const signed char* Ab = A + (size_t)(bm * 128) * 1024;
    const signed char* Wb = W + (size_t)(bn * 128) * 1024;

    auto STAGE = [&](int kt, int buf) {
        int k0 = kt * 128;
        char* Ad = As + buf * 16384;
        char* Bd = Bs + buf * 16384;
#pragma unroll
        for (int j = 0; j < 4; ++j) {
            int c = j * 4 + w;  // 1KB chunk (8 rows x 128B), wave-uniform LDS base
            gload_lds16(Ab + (size_t)(c * 8 + srow) * 1024 + k0 + scolb, Ad + c * 1024);
            gload_lds16(Wb + (size_t)(c * 8 + srow) * 1024 + k0 + scolb, Bd + c * 1024);
        }
    };

    STAGE(0, 0);
    __syncthreads();  // vmcnt(0) drain: buf0 ready
    for (int kt = 0; kt < 8; ++kt) {
        int cur = kt & 1;
        if (kt < 7) STAGE(kt + 1, cur ^ 1);  // prefetch rides under compute
        const char* Ar = As + cur * 16384;
        const char* Br = Bs + cur * 16384;
#pragma unroll
        for (int ks = 0; ks < 2; ++ks) {
            int kb = (ks * 64 + lh * 16) ^ key16;
            i32x4 af[4], bfr[4];
#pragma unroll
            for (int mi = 0; mi < 4; ++mi) af[mi] = *(const i32x4*)&Ar[(wr * 64 + mi * 16 + lr) * 128 + kb];
#pragma unroll
            for (int ni = 0; ni < 4; ++ni) bfr[ni] = *(const i32x4*)&Br[(wc * 64 + ni * 16 + lr) * 128 + kb];
#pragma unroll
            for (int mi = 0; mi < 4; ++mi)
#pragma unroll
                for (int ni = 0; ni < 4; ++ni) acc[mi][ni] = mfma_i8(af[mi], bfr[ni], acc[mi][ni]);
        }
        __syncthreads();  // drains prefetch + read/write fence
    }
#pragma unroll
    for (int mi = 0; mi < 4; ++mi) {
        int mbase = bm * 128 + wr * 64 + mi * 16 + lh * 4;
#pragma unroll
        for (int ni = 0; ni < 4; ++ni) {
            int n = bn * 128 + wc * 64 + ni * 16 + lr;
            if (MODE == 1) {
                int b = mbase >> 11, t0 = mbase & 2047;
                int h = n >> 6, d = n & 63;
                ushort4 st;
                st.x = f2bf((float)acc[mi][ni][0] * s_w / asc[mbase + 0]);
                st.y = f2bf((float)acc[mi][ni][1] * s_w / asc[mbase + 1]);
                st.z = f2bf((float)acc[mi][ni][2] * s_w / asc[mbase + 2]);
                st.w = f2bf((float)acc[mi][ni][3] * s_w / asc[mbase + 3]);
                *(ushort4*)&((unsigned short*)outp)[(size_t)(b * 16 + h) * 131072 + (size_t)d * 2048 + t0] = st;
            } else {
#pragma unroll
                for (int i = 0; i < 4; ++i) {
                    int m = mbase + i;
                    float val = (float)acc[mi][ni][i] * s_w / asc[m];
                    if (MODE == 0) {
                        int b = m >> 11, t = m & 2047, h = n >> 6, d = n & 63;
                        ((unsigned short*)outp)[(size_t)(b * 16 + h) * 131072 + (size_t)t * 64 + d] = f2bf(val);
                    } else {
                        ((float*)outp)[(size_t)m * 1024 + n] = val;
                    }
                }
            }
        }
    }
}

__device__ __forceinline__ float sw_from_part(const float* part) {
    float s = 0.f;
#pragma unroll
    for (int i = 0; i < 32; ++i) s += part[i];
    return fmaxf(s * (1.f / 1048576.f), 1e-5f);
}

// fused Q/K/V projection: blockIdx.z picks the gemm (0=q,1=k,2=v)
__global__ __launch_bounds__(256) void gemm_qkv(const signed char* __restrict__ abf,
                                                const float* __restrict__ ascale,
                                                const signed char* __restrict__ wq8,
                                                const float* __restrict__ part,
                                                unsigned short* __restrict__ qbf,
                                                unsigned short* __restrict__ kbf,
                                                unsigned short* __restrict__ vtb) {
    __shared__ alignas(16) char As[32768];  // 2 x 16KB dbuf
    __shared__ alignas(16) char Bs[32768];
    int z = blockIdx.z;
    const signed char* A = abf + (size_t)z * 4194304;
    const float* asc = ascale + z * 4096;
    const signed char* W = wq8 + (size_t)z * 1048576;
    float s_w = sw_from_part(part + z * 32);
    int bm = blockIdx.x, bn = blockIdx.y;
    if (z == 0) {
        gemm_core<0>(A, asc, W, s_w, qbf, bm, bn, As, Bs);
    } else if (z == 1) {
        gemm_core<0>(A, asc, W, s_w, kbf, bm, bn, As, Bs);
    } else {
        gemm_core<1>(A, asc, W, s_w, vtb, bm, bn, As, Bs);
    }
}

// output projection: f32 out
__global__ __launch_bounds__(256) void gemm_o(const signed char* __restrict__ A,
                                              const float* __restrict__ asc,
                                              const signed char* __restrict__ W,
                                              const float* __restrict__ part, float* __restrict__ outp) {
    __shared__ alignas(16) char As[32768];
    __shared__ alignas(16) char Bs[32768];
    float s_w = sw_from_part(part);
    gemm_core<2>(A, asc, W, s_w, outp, blockIdx.x, blockIdx.y, As, Bs);
}

// ---------------- flash attention (causal, 16 heads, D=64) ------------------
// 512 blocks x 4 waves. Block g covers 128 q-rows of head bh; wave w owns the
// 32-row chunk c_w = 4g+w. Each kv-tile (32 kv) is staged ONCE into LDS via
// global_load_lds (K 4KB + V 4KB, 2 insts/wave), double-buffered, one barrier
// per tile -> global K/V traffic /4 vs per-wave streams (532MB -> 139MB).
// LDS XOR swizzle (rule #21: pre-swizzled global source + same XOR on read):
//   K[row][c16] at slot c16^(row&7)  (row stride 128B)
//   V[d][c16]   at slot c16^(d&3)    (row stride 64B)
// Per-wave math identical to round-9: swapped QK^T, exp2 softmax, diagonal
// mask on t==c_w, defer-max THR=11, setprio around MFMA clusters.
__global__ __launch_bounds__(256) void attn(const unsigned short* __restrict__ qb,
                                            const unsigned short* __restrict__ kb,
                                            const unsigned short* __restrict__ vt, float* __restrict__ y) {
    int blk = blockIdx.x;
    int bh = blk & 31;
    int g = 15 - (blk >> 5);  // 128-row group, heaviest first
    int w = threadIdx.x >> 6;
    int l = threadIdx.x & 63;
    int lr = l & 15, lh = l >> 4;
    int cw = 4 * g + w;       // this wave's 32-row chunk
    int q0 = cw << 5;
    int NT = 4 * g + 4;       // kv-tiles staged by this block

    const unsigned short* qbase = qb + (size_t)bh * 131072;
    const char* kbytes = (const char*)(kb + (size_t)bh * 131072);
    const char* vbytes = (const char*)(vt + (size_t)bh * 131072);

    bf16x8 qf00 = *(const bf16x8*)&qbase[(size_t)(q0 + lr) * 64 + lh * 8];
    bf16x8 qf01 = *(const bf16x8*)&qbase[(size_t)(q0 + lr) * 64 + 32 + lh * 8];
    bf16x8 qf10 = *(const bf16x8*)&qbase[(size_t)(q0 + 16 + lr) * 64 + lh * 8];
    bf16x8 qf11 = *(const bf16x8*)&qbase[(size_t)(q0 + 16 + lr) * 64 + 32 + lh * 8];

    f32x4 o[4][2] = {};  // [dt][qt]
    const float ninf = -__builtin_inff();
    const float SC = 0.125f * 1.44269504f;  // 1/sqrt(64) * log2(e)
    float mreg0 = ninf, mreg1 = ninf;       // running max (log2 domain)
    float lreg0 = 0.f, lreg1 = 0.f;

    __shared__ alignas(16) char Ks[2][4096];   // [buf][32 rows x 128B], swizzled
    __shared__ alignas(16) char Vs[2][4096];   // [buf][64 rows x 64B],  swizzled
    __shared__ alignas(16) unsigned short plds[4][2][16][40];

    int qrow0 = q0 + lr, qrow1 = q0 + 16 + lr;

    // cooperative stage of kv-tile t into buffer buf (all 4 waves, 2 insts each)
    auto STAGE = [&](int t, int buf) {
        int kv0 = t << 5;
        // K: wave w stages rows w*8+(l>>3); source col pre-swizzled by row&7
        gload_lds16(kbytes + (size_t)(kv0 + w * 8 + (l >> 3)) * 128 + (((l & 7) ^ (l >> 3)) * 16),
                    &Ks[buf][w * 1024]);
        // V: wave w stages rows w*16+(l>>2); source col16 pre-swizzled by row&3
        gload_lds16(vbytes + (size_t)(w * 16 + (l >> 2)) * 4096 + (size_t)kv0 * 2 +
                        (((l & 3) ^ ((l >> 2) & 3)) * 16),
                    &Vs[buf][w * 1024]);
    };

    auto PROCESS = [&](int t, const char* Kb, const char* Vb) {
        int kv0 = t << 5;
        // K fragments from swizzled LDS: logical (row, c16) at slot c16^(row&7)
        int k7 = lr & 7;
        bf16x8 k0 = *(const bf16x8*)(Kb + lr * 128 + ((lh ^ k7) * 16));
        bf16x8 k1 = *(const bf16x8*)(Kb + lr * 128 + (((4 + lh) ^ k7) * 16));
        bf16x8 k2 = *(const bf16x8*)(Kb + (16 + lr) * 128 + ((lh ^ k7) * 16));
        bf16x8 k3 = *(const bf16x8*)(Kb + (16 + lr) * 128 + (((4 + lh) ^ k7) * 16));
        __builtin_amdgcn_s_setprio(1);
        f32x4 s00 = {}, s01 = {}, s10 = {}, s11 = {};
        s00 = mfma16(k0, qf00, s00);
        s00 = mfma16(k1, qf01, s00);
        s01 = mfma16(k2, qf00, s01);
        s01 = mfma16(k3, qf01, s01);
        s10 = mfma16(k0, qf10, s10);
        s10 = mfma16(k1, qf11, s10);
        s11 = mfma16(k2, qf10, s11);
        s11 = mfma16(k3, qf11, s11);
        __builtin_amdgcn_s_setprio(0);
        float p0[8], p1[8];
        if (t == cw) {
#pragma unroll
            for (int r = 0; r < 4; ++r) {
                int kva = kv0 + lh * 4 + r, kvb = kv0 + 16 + lh * 4 + r;
                p0[r]     = (kva <= qrow0) ? s00[r] * SC : ninf;
                p0[r + 4] = (kvb <= qrow0) ? s01[r] * SC : ninf;
                p1[r]     = (kva <= qrow1) ? s10[r] * SC : ninf;
                p1[r + 4] = (kvb <= qrow1) ? s11[r] * SC : ninf;
            }
        } else {
#pragma unroll
            for (int r = 0; r < 4; ++r) {
                p0[r] = s00[r] * SC;
                p0[r + 4] = s01[r] * SC;
                p1[r] = s10[r] * SC;
                p1[r + 4] = s11[r] * SC;
            }
        }
        float t0 = fmaxf(fmaxf(fmaxf(p0[0], p0[1]), fmaxf(p0[2], p0[3])),
                         fmaxf(fmaxf(p0[4], p0[5]), fmaxf(p0[6], p0[7])));
        float t1 = fmaxf(fmaxf(fmaxf(p1[0], p1[1]), fmaxf(p1[2], p1[3])),
                         fmaxf(fmaxf(p1[4], p1[5]), fmaxf(p1[6], p1[7])));
        t0 = fmaxf(t0, __shfl_xor(t0, 16));
        t0 = fmaxf(t0, __shfl_xor(t0, 32));
        t1 = fmaxf(t1, __shfl_xor(t1, 16));
        t1 = fmaxf(t1, __shfl_xor(t1, 32));
        if (__any((t0 > mreg0 + 11.f) || (t1 > mreg1 + 11.f))) {
            float mn0 = fmaxf(mreg0, t0), mn1 = fmaxf(mreg1, t1);
            float cc0 = exp2_fast(mreg0 - mn0), cc1 = exp2_fast(mreg1 - mn1);
            lreg0 *= cc0;
            lreg1 *= cc1;
            mreg0 = mn0;
            mreg1 = mn1;
#pragma unroll
            for (int dt = 0; dt < 4; ++dt)
#pragma unroll
                for (int r = 0; r < 4; ++r) {
                    o[dt][0][r] *= cc0;
                    o[dt][1][r] *= cc1;
                }
        }
        float ps0[8], ps1[8];
#pragma unroll
        for (int r = 0; r < 8; ++r) {
            ps0[r] = exp2_fast(p0[r] - mreg0);
            ps1[r] = exp2_fast(p1[r] - mreg1);
        }
        float sum0 = ((ps0[0] + ps0[1]) + (ps0[2] + ps0[3])) + ((ps0[4] + ps0[5]) + (ps0[6] + ps0[7]));
        float sum1 = ((ps1[0] + ps1[1]) + (ps1[2] + ps1[3])) + ((ps1[4] + ps1[5]) + (ps1[6] + ps1[7]));
        sum0 += __shfl_xor(sum0, 16);
        sum0 += __shfl_xor(sum0, 32);
        sum1 += __shfl_xor(sum1, 16);
        sum1 += __shfl_xor(sum1, 32);
        lreg0 += sum0;
        lreg1 += sum1;
        uint2 w0lo, w0hi, w1lo, w1hi;
        w0lo.x = cvtpk_bf16(ps0[0], ps0[1]);
        w0lo.y = cvtpk_bf16(ps0[2], ps0[3]);
        w0hi.x = cvtpk_bf16(ps0[4], ps0[5]);
        w0hi.y = cvtpk_bf16(ps0[6], ps0[7]);
        w1lo.x = cvtpk_bf16(ps1[0], ps1[1]);
        w1lo.y = cvtpk_bf16(ps1[2], ps1[3]);
        w1hi.x = cvtpk_bf16(ps1[4], ps1[5]);
        w1hi.y = cvtpk_bf16(ps1[6], ps1[7]);
        *(uint2*)&plds[w][0][lr][lh * 4] = w0lo;
        *(uint2*)&plds[w][0][lr][16 + lh * 4] = w0hi;
        *(uint2*)&plds[w][1][lr][lh * 4] = w1lo;
        *(uint2*)&plds[w][1][lr][16 + lh * 4] = w1hi;
        bf16x8 pf0 = *(const bf16x8*)&plds[w][0][lr][lh * 8];
        bf16x8 pf1 = *(const bf16x8*)&plds[w][1][lr][lh * 8];
        // V fragments from swizzled LDS: logical (d, c16=lh) at slot lh^(d&3)
        __builtin_amdgcn_s_setprio(1);
#pragma unroll
        for (int dt = 0; dt < 4; ++dt) {
            int d = dt * 16 + lr;
            bf16x8 vv = *(const bf16x8*)(Vb + d * 64 + ((lh ^ (lr & 3)) * 16));
            o[dt][0] = mfma16(vv, pf0, o[dt][0]);
            o[dt][1] = mfma16(vv, pf1, o[dt][1]);
        }
        __builtin_amdgcn_s_setprio(0);
    };

    STAGE(0, 0);
    __syncthreads();  // vmcnt drain: buf0 ready
    for (int t = 0; t < NT; ++t) {
        int buf = t & 1;
        if (t + 1 < NT) STAGE(t + 1, buf ^ 1);  // prefetch rides under compute
        if (t <= cw) PROCESS(t, Ks[buf], Vs[buf]);
        __syncthreads();  // drains prefetch + read/write fence
    }

    int b = bh >> 4, h = bh & 15;
#pragma unroll
    for (int qt = 0; qt < 2; ++qt) {
        int qrow = (qt == 0) ? qrow0 : qrow1;
        float invl = 1.f / ((qt == 0) ? lreg0 : lreg1);
        float* yr = y + (size_t)(b * 2048 + qrow) * 1024 + h * 64;
#pragma unroll
        for (int dt = 0; dt < 4; ++dt) {
            float4 st;
            st.x = o[dt][qt][0] * invl;
            st.y = o[dt][qt][1] * invl;
            st.z = o[dt][qt][2] * invl;
            st.w = o[dt][qt][3] * invl;
            *(float4*)&yr[dt * 16 + lh * 4] = st;
        }
    }
}

extern "C" void kernel_launch(void* const* d_in, const int* in_sizes, int n_in,
                              void* d_out, int out_size, void* d_ws, size_t ws_size,
                              hipStream_t stream) {
    const float* x  = (const float*)d_in[0];
    const float* wq = (const float*)d_in[1];
    const float* wk = (const float*)d_in[2];
    const float* wv = (const float*)d_in[3];
    const float* wo = (const float*)d_in[4];
    const float* gq = (const float*)d_in[5];
    const float* gk = (const float*)d_in[6];
    const float* gv = (const float*)d_in[7];
    const float* go = (const float*)d_in[8];

    char* ws = (char*)d_ws;
    size_t off = 0;
    auto alloc = [&](size_t bytes) {
        size_t o = off;
        off += (bytes + 255) & ~(size_t)255;
        return o;
    };
    float* part = (float*)(ws + alloc(128 * 4));
    signed char* wq8 = (signed char*)(ws + alloc(4ull * 1048576));             // 4 x [1024][1024] i8
    signed char* abf = (signed char*)(ws + alloc(3ull * 4194304));             // 3 x [4096][1024] i8
    float* asc = (float*)(ws + alloc(3ull * 4096 * 4));
    unsigned short* qbf = (unsigned short*)(ws + alloc(4194304ull * 2));       // [BH][T][D] bf16
    unsigned short* kbf = (unsigned short*)(ws + alloc(4194304ull * 2));       // [BH][T][D] bf16
    unsigned short* vtb = (unsigned short*)(ws + alloc(4194304ull * 2));       // [BH][D][T] bf16
    float* ybuf = (float*)(ws + alloc(4194304ull * 4));                        // [B,T,C] f32
    signed char* ybf = (signed char*)(ws + alloc(4194304ull));                 // [M][C] i8
    float* ysc = (float*)(ws + alloc(4096 * 4));
    (void)ws_size; (void)in_sizes; (void)n_in; (void)out_size;

    wabssum<<<128, 256, 0, stream>>>(wq, wk, wv, wo, part);
    wquant<<<256, 256, 0, stream>>>(wq, wk, wv, wo, part, wq8);
    actquant<3><<<4096, 256, 0, stream>>>(x, gq, gk, gv, abf, asc);
    gemm_qkv<<<dim3(32, 8, 3), 256, 0, stream>>>(abf, asc, wq8, part, qbf, kbf, vtb);
    attn<<<512, 256, 0, stream>>>(qbf, kbf, vtb, ybuf);
    actquant<1><<<4096, 256, 0, stream>>>(ybuf, go, go, go, ybf, ysc);
    gemm_o<<<dim3(32, 8), 256, 0, stream>>>(ybf, ysc, wq8 + 3ull * 1048576, part + 96, (float*)d_out);
}